// Round 6
// baseline (1343.745 us; speedup 1.0000x reference)
//
#include <hip/hip_runtime.h>
#include <hip/hip_cooperative_groups.h>

namespace cg = cooperative_groups;

// Problem constants
constexpr int Bn  = 128;
constexpr int Tn  = 48000;
constexpr int NFn = 2999;   // fast frames
constexpr int NSn = 999;    // slow frames
constexpr int G3n = 192;    // 3*GH
constexpr int GHn = 64;

typedef float f2 __attribute__((ext_vector_type(2)));
typedef float f4 __attribute__((ext_vector_type(4)));

// ---------------------------------------------------------------------------
// Kernel 1 (fallback path only): GI = x-frames @ W_ih^T + b_ih
// ---------------------------------------------------------------------------
__global__ __launch_bounds__(192) void gi_kernel(const float* __restrict__ x,
                                                 const float* __restrict__ W_ih,
                                                 const float* __restrict__ b_ih,
                                                 float* __restrict__ GI) {
  __shared__ __align__(16) float WT[48 * 196];   // [k][j] padded stride 196
  __shared__ float xs[1584];                     // 31*48+96 samples
  const int tile = blockIdx.x;        // 0..31
  const int b    = blockIdx.y;        // 0..127
  const int t0   = tile * 32;
  const int nt   = min(32, NSn - t0); // 32 or 7 (last tile)
  const int tid  = threadIdx.x;

  const int span = (nt - 1) * 48 + 96;
  for (int i = tid; i < 1584; i += 192)
    xs[i] = (i < span) ? x[(size_t)b * Tn + t0 * 48 + i] : 0.0f;

  const int jq = tid % 48;   // j-quad index
  const int tg = tid / 48;   // t-group (0..3)
  const int j0 = jq * 4;

  float acc[8][4];
#pragma unroll
  for (int u = 0; u < 8; ++u)
#pragma unroll
    for (int jj = 0; jj < 4; ++jj) acc[u][jj] = b_ih[j0 + jj];

  for (int half = 0; half < 2; ++half) {
    __syncthreads();
    for (int e = tid; e < 192 * 48; e += 192) {
      int j = e / 48, k = e % 48;
      WT[k * 196 + j] = W_ih[j * 96 + half * 48 + k];
    }
    __syncthreads();
    for (int k = 0; k < 48; ++k) {
      float4 w = *(const float4*)&WT[k * 196 + j0];
#pragma unroll
      for (int u = 0; u < 8; ++u) {
        float xv = xs[(tg * 8 + u) * 48 + half * 48 + k];
        acc[u][0] = fmaf(xv, w.x, acc[u][0]);
        acc[u][1] = fmaf(xv, w.y, acc[u][1]);
        acc[u][2] = fmaf(xv, w.z, acc[u][2]);
        acc[u][3] = fmaf(xv, w.w, acc[u][3]);
      }
    }
  }

#pragma unroll
  for (int u = 0; u < 8; ++u) {
    int tl = tg * 8 + u;
    if (tl < nt) {
      float4 st = make_float4(acc[u][0], acc[u][1], acc[u][2], acc[u][3]);
      *(float4*)&GI[(size_t)(b * NSn + t0 + tl) * G3n + j0] = st;
    }
  }
}

// ---------------------------------------------------------------------------
// GRU body (round-0 proven, 485us). POLL=true adds per-32-step-chunk flag
// waits for the producer-consumer mega kernel.
// ---------------------------------------------------------------------------
__device__ __forceinline__ float fsigmoid(float v) {
  return __fdividef(1.0f, 1.0f + __expf(-v));
}
__device__ __forceinline__ float ftanh_f(float v) {
  return 1.0f - __fdividef(2.0f, __expf(2.0f * v) + 1.0f);
}

template <bool POLL>
__device__ __forceinline__ void gru_body(const float* __restrict__ GI,
                                         const float* __restrict__ W_hh,
                                         const float* __restrict__ b_hh,
                                         float* __restrict__ hs,
                                         float* hbuf, int b, int j,
                                         unsigned int* flags) {
  f2 wr2[32], wz2[32], wn2[32];
  const f2* Wr = (const f2*)(W_hh + (size_t)j * 64);
  const f2* Wz = (const f2*)(W_hh + (size_t)(j + 64) * 64);
  const f2* Wn = (const f2*)(W_hh + (size_t)(j + 128) * 64);
#pragma unroll
  for (int q = 0; q < 32; ++q) { wr2[q] = Wr[q]; wz2[q] = Wz[q]; wn2[q] = Wn[q]; }
  // Opaque to the compiler => cannot re-load from memory inside the loop.
#pragma unroll
  for (int q = 0; q < 32; ++q) {
    asm volatile("" : "+v"(wr2[q]));
    asm volatile("" : "+v"(wz2[q]));
    asm volatile("" : "+v"(wn2[q]));
  }
  const float br = b_hh[j], bz = b_hh[j + 64], bn = b_hh[j + 128];

  unsigned int* fl = POLL ? (flags + b * 32) : nullptr;
  int cur_tc = 0;
  if (POLL) {
    if (j == 0) {
      while (__hip_atomic_load(&fl[0], __ATOMIC_ACQUIRE,
                               __HIP_MEMORY_SCOPE_AGENT) < 3u)
        __builtin_amdgcn_s_sleep(4);
    }
    __builtin_amdgcn_wave_barrier();
    __threadfence();
  }

  hbuf[j] = 0.0f;
  float hj = 0.0f;
  __builtin_amdgcn_wave_barrier();

  const float* gp = GI + (size_t)b * NSn * G3n;
  float* hsp = hs + (size_t)b * NSn * GHn;

  // distance-2 prefetch ring
  float pr0, pr1, pr2, pz0, pz1, pz2, pn0, pn1, pn2;
  pr0 = gp[0 * G3n + j];       pz0 = gp[0 * G3n + 64 + j];  pn0 = gp[0 * G3n + 128 + j];
  pr1 = gp[1 * G3n + j];       pz1 = gp[1 * G3n + 64 + j];  pn1 = gp[1 * G3n + 128 + j];

  for (int t = 0; t < NSn; ++t) {
    const int tn = min(t + 2, NSn - 1);
    if (POLL) {
      const int tc2 = tn >> 5;
      if (tc2 != cur_tc) {
        if (j == 0) {
          while (__hip_atomic_load(&fl[tc2], __ATOMIC_ACQUIRE,
                                   __HIP_MEMORY_SCOPE_AGENT) < 3u)
            __builtin_amdgcn_s_sleep(4);
        }
        __builtin_amdgcn_wave_barrier();
        __threadfence();
        cur_tc = tc2;
      }
    }
    const size_t off = (size_t)tn * G3n;
    pr2 = gp[off + j];
    pz2 = gp[off + 64 + j];
    pn2 = gp[off + 128 + j];

    const f2* h2 = (const f2*)hbuf;
    f2 ar0 = {0.f, 0.f}, ar1 = {0.f, 0.f}, ar2 = {0.f, 0.f}, ar3 = {0.f, 0.f};
    f2 az0 = {0.f, 0.f}, az1 = {0.f, 0.f}, az2 = {0.f, 0.f}, az3 = {0.f, 0.f};
    f2 an0 = {0.f, 0.f}, an1 = {0.f, 0.f}, an2 = {0.f, 0.f}, an3 = {0.f, 0.f};
#pragma unroll
    for (int q = 0; q < 8; ++q) {
      f2 h0 = h2[q * 4 + 0], h1 = h2[q * 4 + 1], h2v = h2[q * 4 + 2], h3 = h2[q * 4 + 3];
      ar0 += wr2[q * 4 + 0] * h0; ar1 += wr2[q * 4 + 1] * h1;
      ar2 += wr2[q * 4 + 2] * h2v; ar3 += wr2[q * 4 + 3] * h3;
      az0 += wz2[q * 4 + 0] * h0; az1 += wz2[q * 4 + 1] * h1;
      az2 += wz2[q * 4 + 2] * h2v; az3 += wz2[q * 4 + 3] * h3;
      an0 += wn2[q * 4 + 0] * h0; an1 += wn2[q * 4 + 1] * h1;
      an2 += wn2[q * 4 + 2] * h2v; an3 += wn2[q * 4 + 3] * h3;
    }
    f2 sr = (ar0 + ar1) + (ar2 + ar3);
    f2 sz = (az0 + az1) + (az2 + az3);
    f2 sn = (an0 + an1) + (an2 + an3);

    float r = fsigmoid(pr0 + br + sr.x + sr.y);
    float z = fsigmoid(pz0 + bz + sz.x + sz.y);
    float n = ftanh_f(fmaf(r, bn + sn.x + sn.y, pn0));
    float hn = fmaf(z, hj - n, n);          // (1-z)*n + z*h

    __builtin_amdgcn_wave_barrier();
    hbuf[j] = hn;
    __builtin_amdgcn_wave_barrier();
    hj = hn;
    hsp[(size_t)t * GHn + j] = hn;

    pr0 = pr1; pr1 = pr2;
    pz0 = pz1; pz1 = pz2;
    pn0 = pn1; pn1 = pn2;
  }
}

// Standalone gru (fallback path) — round-0 exact behavior.
__global__ __attribute__((amdgpu_flat_work_group_size(64, 64),
                          amdgpu_waves_per_eu(1, 1),
                          amdgpu_num_vgpr(256)))
void gru_kernel(const float* __restrict__ GI,
                const float* __restrict__ W_hh,
                const float* __restrict__ b_hh,
                float* __restrict__ hs) {
  __shared__ __align__(16) float hbuf[64];
  gru_body<false>(GI, W_hh, b_hh, hs, hbuf, blockIdx.x, threadIdx.x, nullptr);
}

// ---------------------------------------------------------------------------
// FAT kernel (fallback if cooperative launch is rejected): gru + U filler.
// ---------------------------------------------------------------------------
constexpr int UCHUNK = 125;
constexpr int NCH    = 24;            // 24*125 = 3000 >= 2999

__global__ __attribute__((amdgpu_flat_work_group_size(64, 64),
                          amdgpu_waves_per_eu(1, 1),
                          amdgpu_num_vgpr(256)))
void fat_kernel(const float* __restrict__ GI,
                const float* __restrict__ W_hh,
                const float* __restrict__ b_hh,
                float* __restrict__ hs,
                const float* __restrict__ x,
                const float* __restrict__ W1,
                const float* __restrict__ b1,
                float* __restrict__ U) {
  __shared__ __align__(16) float hbuf[64];
  __shared__ __align__(16) float xs[UCHUNK * 16 + 16];   // 2016
  const int tid = threadIdx.x;

  if (blockIdx.x < Bn) {
    gru_body<false>(GI, W_hh, b_hh, hs, hbuf, blockIdx.x, tid, nullptr);
    return;
  }

  const int ub = blockIdx.x - Bn;
  const int b  = ub / NCH;
  const int ch = ub % NCH;
  const int fA = ch * UCHUNK;
  const int fE = min(fA + UCHUNK, NFn);
  const int o  = tid;

  const int nsamp = (fE - fA - 1) * 16 + 32;
  for (int i = tid; i < nsamp; i += 64)
    xs[i] = x[(size_t)b * Tn + fA * 16 + i];

  f4 w1f[8];
#pragma unroll
  for (int i = 0; i < 8; ++i)
    w1f[i] = *(const f4*)&W1[(size_t)o * 64 + 4 * i];
  const float bo = b1[o];
  __syncthreads();

  float* Up = U + ((size_t)b * NFn) * GHn + o;
  for (int f = fA; f < fE; ++f) {
    const f4* xq = (const f4*)&xs[(f - fA) * 16];
    float a0 = bo, a1 = 0.f, a2 = 0.f, a3 = 0.f;
#pragma unroll
    for (int i = 0; i < 8; ++i) {
      f4 xv = xq[i];
      a0 = fmaf(xv[0], w1f[i][0], a0);
      a1 = fmaf(xv[1], w1f[i][1], a1);
      a2 = fmaf(xv[2], w1f[i][2], a2);
      a3 = fmaf(xv[3], w1f[i][3], a3);
    }
    Up[(size_t)f * GHn] = (a0 + a1) + (a2 + a3);
  }
}

// ---------------------------------------------------------------------------
// MEGA cooperative kernel: 1024 blocks x 64 thr (1 wave/SIMD, co-resident).
//  blocks [0,896):    workers — gi tiles (t-major, flag-signalled), then U.
//  blocks [896,1024): gru with per-32-step-chunk flag polling.
// gi tile = (b, tc of 32 steps, gate g of 64 rows); FLOP order identical to
// gi_kernel => bitwise-identical GI. Producer->consumer handoff uses
// __threadfence + agent-scope atomics (XCD-safe; cooperative launch
// guarantees co-residency — no dispatch-order assumption).
// R5 BUG FIX: U-phase staging previously used smem+1536 (only 1632 floats
// left) for a 2016-float buffer -> LDS out-of-bounds -> absmax 0.56. Now
// stages at smem base (free after the gi phase completes for this block).
// ---------------------------------------------------------------------------
constexpr int NWORK  = 896;
constexpr int NBLK   = 1024;
constexpr int GTILES = Bn * 32 * 3;   // 12288

__global__ __attribute__((amdgpu_flat_work_group_size(64, 64),
                          amdgpu_waves_per_eu(1, 1),
                          amdgpu_num_vgpr(256)))
void mega_kernel(float* __restrict__ GI,
                 const float* __restrict__ W_hh,
                 const float* __restrict__ b_hh,
                 float* __restrict__ hs,
                 const float* __restrict__ x,
                 const float* __restrict__ W_ih,
                 const float* __restrict__ b_ih,
                 const float* __restrict__ W1,
                 const float* __restrict__ b1,
                 float* __restrict__ U,
                 unsigned int* __restrict__ flags) {
  __shared__ __align__(16) float smem[3168];   // union: gru 64 | gi 1536+1584 | U 2016
  const int tid = threadIdx.x;

  // phase 0: zero flags (re-done every graph replay), then grid-wide sync
  for (int i = blockIdx.x * 64 + tid; i < Bn * 32; i += NBLK * 64)
    flags[i] = 0u;
  __threadfence();
  cg::this_grid().sync();

  if (blockIdx.x >= NWORK) {
    gru_body<true>(GI, W_hh, b_hh, hs, smem, blockIdx.x - NWORK, tid, flags);
    return;
  }

  // ---------------- worker: gi tiles ----------------
  float* WQ = smem;           // 24k x 64j = 1536
  float* xs = smem + 1536;    // 1584
  const int jq = tid & 15;
  const int tg = tid >> 4;
  const int j0 = jq * 4;

  for (int tile = blockIdx.x; tile < GTILES; tile += NWORK) {
    const int tc = tile / (Bn * 3);        // t-major: layer 0 first
    const int rr = tile - tc * (Bn * 3);
    const int b  = rr / 3;
    const int g  = rr - b * 3;
    const int nt = min(32, NSn - tc * 32);
    const int span = (nt - 1) * 48 + 96;

    __builtin_amdgcn_wave_barrier();
    for (int i = tid; i < 1584; i += 64)
      xs[i] = (i < span) ? x[(size_t)b * Tn + tc * 1536 + i] : 0.0f;

    float acc[8][4];
#pragma unroll
    for (int u = 0; u < 8; ++u)
#pragma unroll
      for (int jj = 0; jj < 4; ++jj) acc[u][jj] = b_ih[g * 64 + j0 + jj];

    for (int q = 0; q < 4; ++q) {
      __builtin_amdgcn_wave_barrier();
      {
        // thread tid stages W row j = g*64+tid, k-quarter q (contiguous 24)
        const float* src = &W_ih[(size_t)(g * 64 + tid) * 96 + q * 24];
#pragma unroll
        for (int i2 = 0; i2 < 6; ++i2) {
          f4 v = *(const f4*)&src[4 * i2];
#pragma unroll
          for (int c = 0; c < 4; ++c) WQ[(i2 * 4 + c) * 64 + tid] = v[c];
        }
      }
      __builtin_amdgcn_wave_barrier();
      for (int k = 0; k < 24; ++k) {
        f4 w = *(const f4*)&WQ[k * 64 + j0];
#pragma unroll
        for (int u = 0; u < 8; ++u) {
          float xv = xs[(tg * 8 + u) * 48 + q * 24 + k];
          acc[u][0] = fmaf(xv, w[0], acc[u][0]);
          acc[u][1] = fmaf(xv, w[1], acc[u][1]);
          acc[u][2] = fmaf(xv, w[2], acc[u][2]);
          acc[u][3] = fmaf(xv, w[3], acc[u][3]);
        }
      }
    }

#pragma unroll
    for (int u = 0; u < 8; ++u) {
      int tl = tg * 8 + u;
      if (tl < nt) {
        float4 st = make_float4(acc[u][0], acc[u][1], acc[u][2], acc[u][3]);
        *(float4*)&GI[((size_t)(b * NSn + tc * 32 + tl)) * G3n + g * 64 + j0] = st;
      }
    }
    __threadfence();   // make GI stores agent-visible before the flag
    if (tid == 0)
      __hip_atomic_fetch_add(&flags[b * 32 + tc], 1u, __ATOMIC_RELEASE,
                             __HIP_MEMORY_SCOPE_AGENT);
  }

  // ---------------- worker: U tiles ----------------
  // FIX: stage at smem base (2016 <= 3168 floats). gi phase for this block
  // is complete; wave barriers order LDS reuse within the single wave.
  float* xu = smem;
  f4 w1f[8];
#pragma unroll
  for (int i = 0; i < 8; ++i)
    w1f[i] = *(const f4*)&W1[(size_t)tid * 64 + 4 * i];
  const float bo = b1[tid];

  for (int ut = blockIdx.x; ut < Bn * NCH; ut += NWORK) {
    const int b  = ut / NCH;
    const int ch = ut % NCH;
    const int fA = ch * UCHUNK;
    const int fE = min(fA + UCHUNK, NFn);
    const int nsamp = (fE - fA - 1) * 16 + 32;

    __builtin_amdgcn_wave_barrier();
    for (int i = tid; i < nsamp; i += 64)
      xu[i] = x[(size_t)b * Tn + fA * 16 + i];
    __builtin_amdgcn_wave_barrier();

    float* Up = U + ((size_t)b * NFn) * GHn + tid;
    for (int f = fA; f < fE; ++f) {
      const f4* xq = (const f4*)&xu[(f - fA) * 16];
      float a0 = bo, a1 = 0.f, a2 = 0.f, a3 = 0.f;
#pragma unroll
      for (int i = 0; i < 8; ++i) {
        f4 xv = xq[i];
        a0 = fmaf(xv[0], w1f[i][0], a0);
        a1 = fmaf(xv[1], w1f[i][1], a1);
        a2 = fmaf(xv[2], w1f[i][2], a2);
        a3 = fmaf(xv[3], w1f[i][3], a3);
      }
      Up[(size_t)f * GHn] = (a0 + a1) + (a2 + a3);
    }
  }
}

// ---------------------------------------------------------------------------
// d_kernel: d[b,ts,o] = (c_s @ W1_cond^T), c_s = hs @ W_cs^T + b_cs  (proven)
// ---------------------------------------------------------------------------
__global__ __launch_bounds__(256) void d_kernel(const float* __restrict__ hs,
                                                const float* __restrict__ W_cs,
                                                const float* __restrict__ b_cs,
                                                const float* __restrict__ W1,
                                                float* __restrict__ d) {
  __shared__ __align__(16) float WcT[64 * 36];   // [k][i] stride 36
  __shared__ __align__(16) float W1cT[32 * 68];  // [i][o] stride 68
  __shared__ __align__(16) float hsl[32 * 65];   // [t][k] stride 65
  __shared__ __align__(16) float cloc[32 * 36];  // [t][i] stride 36
  __shared__ __align__(16) float bcs[32];
  const int tile = blockIdx.x;   // 0..31
  const int b    = blockIdx.y;
  const int t0   = tile * 32;
  const int nt   = min(32, NSn - t0);
  const int tid  = threadIdx.x;

  for (int e = tid; e < 32 * 64; e += 256) {
    int i = e >> 6, k = e & 63;
    WcT[k * 36 + i] = W_cs[e];
  }
  for (int e = tid; e < 64 * 32; e += 256) {
    int o = e >> 5, i = e & 31;
    W1cT[i * 68 + o] = W1[(size_t)o * 64 + 32 + i];
  }
  for (int e = tid; e < nt * 64; e += 256) {
    int t = e >> 6, k = e & 63;
    hsl[t * 65 + k] = hs[((size_t)b * NSn + t0 + t) * GHn + k];
  }
  if (tid < 32) bcs[tid] = b_cs[tid];
  __syncthreads();

  {
    const int iq = tid & 7;
    const int t  = tid >> 3;
    if (t < nt) {
      float4 acc = *(const float4*)&bcs[iq * 4];
      const float* hr = &hsl[t * 65];
#pragma unroll 4
      for (int k = 0; k < 64; ++k) {
        float hv = hr[k];
        float4 w = *(const float4*)&WcT[k * 36 + iq * 4];
        acc.x = fmaf(w.x, hv, acc.x);
        acc.y = fmaf(w.y, hv, acc.y);
        acc.z = fmaf(w.z, hv, acc.z);
        acc.w = fmaf(w.w, hv, acc.w);
      }
      *(float4*)&cloc[t * 36 + iq * 4] = acc;
    }
  }
  __syncthreads();

  for (int it = tid; it < 32 * 16; it += 256) {
    const int oq = it & 15;
    const int t  = it >> 4;
    if (t < nt) {
      float a0 = 0.f, a1 = 0.f, a2 = 0.f, a3 = 0.f;
      const float* cr = &cloc[t * 36];
#pragma unroll 4
      for (int i = 0; i < 32; ++i) {
        float cv = cr[i];
        float4 w = *(const float4*)&W1cT[i * 68 + oq * 4];
        a0 = fmaf(w.x, cv, a0);
        a1 = fmaf(w.y, cv, a1);
        a2 = fmaf(w.z, cv, a2);
        a3 = fmaf(w.w, cv, a3);
      }
      float4 st = make_float4(a0, a1, a2, a3);
      *(float4*)&d[((size_t)b * NSn + t0 + t) * GHn + oq * 4] = st;
    }
  }
}

// ---------------------------------------------------------------------------
// cs_kernel (small-ws fallback only)
// ---------------------------------------------------------------------------
__global__ __launch_bounds__(256) void cs_kernel(const float* __restrict__ hs,
                                                 const float* __restrict__ W_cs,
                                                 const float* __restrict__ b_cs,
                                                 float* __restrict__ cs) {
  __shared__ __align__(16) float WcT[64 * 36];
  __shared__ __align__(16) float hsl[32 * 65];
  __shared__ __align__(16) float bcs[32];
  const int tile = blockIdx.x;
  const int b    = blockIdx.y;
  const int t0   = tile * 32;
  const int nt   = min(32, NSn - t0);
  const int tid  = threadIdx.x;

  for (int e = tid; e < 32 * 64; e += 256) {
    int i = e >> 6, k = e & 63;
    WcT[k * 36 + i] = W_cs[e];
  }
  for (int e = tid; e < nt * 64; e += 256) {
    int t = e >> 6, k = e & 63;
    hsl[t * 65 + k] = hs[((size_t)b * NSn + t0 + t) * GHn + k];
  }
  if (tid < 32) bcs[tid] = b_cs[tid];
  __syncthreads();

  const int oq = tid & 7;
  const int t  = tid >> 3;
  if (t < nt) {
    float4 acc = *(const float4*)&bcs[oq * 4];
    const float* hr = &hsl[t * 65];
#pragma unroll 4
    for (int k = 0; k < 64; ++k) {
      float hv = hr[k];
      float4 w = *(const float4*)&WcT[k * 36 + oq * 4];
      acc.x = fmaf(w.x, hv, acc.x);
      acc.y = fmaf(w.y, hv, acc.y);
      acc.z = fmaf(w.z, hv, acc.z);
      acc.w = fmaf(w.w, hv, acc.w);
    }
    *(float4*)&cs[((size_t)b * NSn + t0 + t) * 32 + oq * 4] = acc;
  }
}

// ---------------------------------------------------------------------------
// out2: h = relu(U + d[ts]), y = h@W2^T + b2, overlap-add  (proven)
// ---------------------------------------------------------------------------
__global__ __launch_bounds__(256) void out2_kernel(const float* __restrict__ U,
                                                   const float* __restrict__ d,
                                                   const float* __restrict__ W2,
                                                   const float* __restrict__ b2,
                                                   float* __restrict__ out) {
  __shared__ __align__(16) float h1loc[33 * 68];
  __shared__ __align__(16) float W2T[64 * 36];
  __shared__ __align__(16) float yloc[33 * 32];
  __shared__ __align__(16) float dloc[12][68];
  __shared__ __align__(16) float bb2[32];

  const int fb  = blockIdx.x;
  const int b   = blockIdx.y;
  const int f0  = fb * 32;
  const int nf  = min(33, NFn - f0);
  const int tid = threadIdx.x;
  const int ts0 = max(f0 / 3 - 1, 0);

  for (int e = tid; e < 32 * 64; e += 256) {
    int o = e >> 6, k = e & 63;
    W2T[k * 36 + o] = W2[e];
  }
  if (tid < 32) bb2[tid] = b2[tid];
  for (int e = tid; e < 12 * 64; e += 256) {
    int ti = e >> 6, o = e & 63;
    int ts = min(ts0 + ti, NSn - 1);
    dloc[ti][o] = d[((size_t)b * NSn + ts) * GHn + o];
  }
  __syncthreads();

  for (int it = tid; it < 33 * 16; it += 256) {
    const int lf = it >> 4, oq = it & 15;
    const int f  = f0 + lf;
    f4 s = {0.f, 0.f, 0.f, 0.f};
    if (f < NFn) {
      f4 u  = *(const f4*)&U[((size_t)b * NFn + f) * GHn + oq * 4];
      const int ti = max(f / 3 - 1, 0) - ts0;
      f4 dv = *(const f4*)&dloc[ti][oq * 4];
      s = u + dv;
#pragma unroll
      for (int c = 0; c < 4; ++c) s[c] = fmaxf(s[c], 0.f);
    }
    *(f4*)&h1loc[lf * 68 + oq * 4] = s;
  }
  __syncthreads();

  for (int it = tid; it < 33 * 8; it += 256) {
    const int lf = it >> 3, oq = it & 7;
    float4 acc = *(const float4*)&bb2[oq * 4];
    const float* hr = &h1loc[lf * 68];
#pragma unroll 4
    for (int k = 0; k < 64; ++k) {
      float hv = hr[k];
      float4 w = *(const float4*)&W2T[k * 36 + oq * 4];
      acc.x = fmaf(w.x, hv, acc.x);
      acc.y = fmaf(w.y, hv, acc.y);
      acc.z = fmaf(w.z, hv, acc.z);
      acc.w = fmaf(w.w, hv, acc.w);
    }
    *(float4*)&yloc[lf * 32 + oq * 4] = acc;
  }
  __syncthreads();

  const int s0 = f0 * 16 + 16;
  const int s1 = min(s0 + 512, Tn);
  for (int s = s0 + tid; s < s1; s += 256) {
    int f1  = s >> 4;
    int o1  = s & 15;
    int lf1 = f1 - f0;
    float v = yloc[(lf1 - 1) * 32 + o1 + 16];
    if (lf1 < nf) v += yloc[lf1 * 32 + o1];
    out[(size_t)b * Tn + s] = v;
  }
  if (fb == 0 && tid < 16) out[(size_t)b * Tn + tid] = yloc[tid];
}

// ---------------------------------------------------------------------------
// out_kernel (small-ws fallback only): round-0 fused MLP + OA
// ---------------------------------------------------------------------------
__global__ __launch_bounds__(256) void out_kernel(const float* __restrict__ x,
                                                  const float* __restrict__ cs,
                                                  const float* __restrict__ W1,
                                                  const float* __restrict__ b1,
                                                  const float* __restrict__ W2,
                                                  const float* __restrict__ b2,
                                                  float* __restrict__ out) {
  __shared__ __align__(16) float A[33 * 65];
  __shared__ __align__(16) float W1T[64 * 68];
  __shared__ __align__(16) float W2T[64 * 36];
  __shared__ __align__(16) float h1loc[33 * 65];
  __shared__ __align__(16) float yloc[33 * 32];
  __shared__ __align__(16) float bb1[64];
  __shared__ __align__(16) float bb2[32];

  const int fb  = blockIdx.x;
  const int b   = blockIdx.y;
  const int f0  = fb * 32;
  const int nf  = min(33, NFn - f0);
  const int tid = threadIdx.x;

  for (int e = tid; e < 64 * 64; e += 256) {
    int o = e >> 6, k = e & 63;
    W1T[k * 68 + o] = W1[e];
  }
  for (int e = tid; e < 32 * 64; e += 256) {
    int o = e >> 6, k = e & 63;
    W2T[k * 36 + o] = W2[e];
  }
  if (tid < 64) bb1[tid] = b1[tid];
  if (tid < 32) bb2[tid] = b2[tid];

  for (int e = tid; e < 33 * 32; e += 256) {
    int lf = e >> 5, k = e & 31;
    int g = (f0 + lf) * 16 + k;
    A[lf * 65 + k] = (lf < nf && g < Tn) ? x[(size_t)b * Tn + g] : 0.0f;
  }
  for (int e = tid; e < 33 * 32; e += 256) {
    int lf = e >> 5, k = e & 31;
    int ts = max((f0 + lf) / 3 - 1, 0);
    A[lf * 65 + 32 + k] = (lf < nf) ? cs[((size_t)b * NSn + ts) * 32 + k] : 0.0f;
  }
  __syncthreads();

  for (int it = tid; it < 33 * 16; it += 256) {
    int lf = it >> 4, oq = it & 15;
    float4 acc = *(const float4*)&bb1[oq * 4];
    const float* ar = &A[lf * 65];
#pragma unroll 4
    for (int k = 0; k < 64; ++k) {
      float av = ar[k];
      float4 w = *(const float4*)&W1T[k * 68 + oq * 4];
      acc.x = fmaf(w.x, av, acc.x);
      acc.y = fmaf(w.y, av, acc.y);
      acc.z = fmaf(w.z, av, acc.z);
      acc.w = fmaf(w.w, av, acc.w);
    }
    acc.x = fmaxf(acc.x, 0.0f); acc.y = fmaxf(acc.y, 0.0f);
    acc.z = fmaxf(acc.z, 0.0f); acc.w = fmaxf(acc.w, 0.0f);
    *(float4*)&h1loc[lf * 65 + oq * 4] = acc;
  }
  __syncthreads();

  for (int it = tid; it < 33 * 8; it += 256) {
    int lf = it >> 3, oq = it & 7;
    float4 acc = *(const float4*)&bb2[oq * 4];
    const float* hr = &h1loc[lf * 65];
#pragma unroll 4
    for (int k = 0; k < 64; ++k) {
      float hv = hr[k];
      float4 w = *(const float4*)&W2T[k * 36 + oq * 4];
      acc.x = fmaf(w.x, hv, acc.x);
      acc.y = fmaf(w.y, hv, acc.y);
      acc.z = fmaf(w.z, hv, acc.z);
      acc.w = fmaf(w.w, hv, acc.w);
    }
    *(float4*)&yloc[lf * 32 + oq * 4] = acc;
  }
  __syncthreads();

  const int s0 = f0 * 16 + 16;
  const int s1 = min(s0 + 512, Tn);
  for (int s = s0 + tid; s < s1; s += 256) {
    int f1  = s >> 4;
    int o1  = s & 15;
    int lf1 = f1 - f0;
    float v = yloc[(lf1 - 1) * 32 + o1 + 16];
    if (lf1 < nf) v += yloc[lf1 * 32 + o1];
    out[(size_t)b * Tn + s] = v;
  }
  if (fb == 0 && tid < 16) out[(size_t)b * Tn + tid] = yloc[tid];
}

// ---------------------------------------------------------------------------
extern "C" void kernel_launch(void* const* d_in, const int* in_sizes, int n_in,
                              void* d_out, int out_size, void* d_ws, size_t ws_size,
                              hipStream_t stream) {
  const float* x    = (const float*)d_in[0];
  const float* W_ih = (const float*)d_in[1];
  const float* W_hh = (const float*)d_in[2];
  const float* b_ih = (const float*)d_in[3];
  const float* b_hh = (const float*)d_in[4];
  const float* W_cs = (const float*)d_in[5];
  const float* b_cs = (const float*)d_in[6];
  const float* W1   = (const float*)d_in[7];
  const float* b1   = (const float*)d_in[8];
  const float* W2   = (const float*)d_in[9];
  const float* b2   = (const float*)d_in[10];
  float* out = (float*)d_out;

  const size_t giN = (size_t)Bn * NSn * G3n;   // 98.2 MB
  const size_t hsN = (size_t)Bn * NSn * GHn;   // 32.7 MB
  const size_t uN  = (size_t)Bn * NFn * GHn;   // 98.3 MB

  float* GI = (float*)d_ws;
  float* hs = GI + giN;

  if (ws_size >= (giN + hsN + uN) * sizeof(float)) {
    float* U = hs + hsN;
    float* d = GI;                             // GI dead after mega/fat
    // flags live in the first 16KB of `out` — fully overwritten by out2.
    unsigned int* flags = (unsigned int*)out;

    void* args[] = {(void*)&GI, (void*)&W_hh, (void*)&b_hh, (void*)&hs,
                    (void*)&x,  (void*)&W_ih, (void*)&b_ih, (void*)&W1,
                    (void*)&b1, (void*)&U,    (void*)&flags};
    hipError_t e = hipLaunchCooperativeKernel((const void*)mega_kernel,
                                              dim3(NBLK), dim3(64),
                                              args, 0, stream);
    if (e != hipSuccess) {
      (void)hipGetLastError();   // clear sticky error, use proven r4 path
      gi_kernel<<<dim3(32, Bn), 192, 0, stream>>>(x, W_ih, b_ih, GI);
      fat_kernel<<<Bn + Bn * NCH, 64, 0, stream>>>(GI, W_hh, b_hh, hs,
                                                   x, W1, b1, U);
    }
    d_kernel<<<dim3(32, Bn), 256, 0, stream>>>(hs, W_cs, b_cs, W1, d);
    out2_kernel<<<dim3(94, Bn), 256, 0, stream>>>(U, d, W2, b2, out);
  } else {
    // Small-ws fallback: proven round-0 pipeline.
    float* cs = GI;
    gi_kernel<<<dim3(32, Bn), 192, 0, stream>>>(x, W_ih, b_ih, GI);
    gru_kernel<<<Bn, 64, 0, stream>>>(GI, W_hh, b_hh, hs);
    cs_kernel<<<dim3(32, Bn), 256, 0, stream>>>(hs, W_cs, b_cs, cs);
    out_kernel<<<dim3(94, Bn), 256, 0, stream>>>(x, cs, W1, b1, W2, b2, out);
  }
}

// Round 7
// 870.103 us; speedup vs baseline: 1.5444x; 1.5444x over previous
//
#include <hip/hip_runtime.h>

// Problem constants
constexpr int Bn  = 128;
constexpr int Tn  = 48000;
constexpr int NFn = 2999;   // fast frames
constexpr int NSn = 999;    // slow frames
constexpr int G3n = 192;    // 3*GH
constexpr int GHn = 64;

typedef float f2 __attribute__((ext_vector_type(2)));
typedef float f4 __attribute__((ext_vector_type(4)));

// ---------------------------------------------------------------------------
// Kernel 1 (NEW): GI[b,t,j] = b_ih[j] + sum_k x[b,t*48+k] * W_ih[j,k]
// W-stationary: thread j holds its full W row in 24 f4 VGPRs (staged once
// through LDS, coalesced). x is read with a wave-UNIFORM address (b, t
// uniform) -> one L1 lookup broadcast to all lanes; the inner loop has ZERO
// LDS traffic (old gi was LDS-pipe-bound at 3 blocks/CU). Two t's per
// iteration give 2 independent FMA chains (single chain = 96x4cy latency).
// FMA order k-ascending, single chain, init b_ih => bitwise-identical GI.
// ---------------------------------------------------------------------------
constexpr int GI_TC = 56;   // t per block
constexpr int GI_NC = 18;   // 18*56 = 1008 >= 999

__global__ __launch_bounds__(192) void gi2_kernel(const float* __restrict__ x,
                                                  const float* __restrict__ W_ih,
                                                  const float* __restrict__ b_ih,
                                                  float* __restrict__ GI) {
  __shared__ __align__(16) float WL[192 * 48];   // one k-half, [row][kk]
  const int b  = blockIdx.y;
  const int t0 = blockIdx.x * GI_TC;
  const int t1 = min(t0 + GI_TC, NSn);
  const int j  = threadIdx.x;                    // gate row 0..191

  f4 w[24];
  for (int h = 0; h < 2; ++h) {
    __syncthreads();
    for (int e = j; e < 192 * 48; e += 192) {
      const int row = e / 48, kk = e - row * 48;
      WL[e] = W_ih[row * 96 + h * 48 + kk];      // coalesced in kk
    }
    __syncthreads();
#pragma unroll
    for (int i = 0; i < 12; ++i)
      w[h * 12 + i] = *(const f4*)&WL[j * 48 + 4 * i];
  }
  const float bj = b_ih[j];

  const float* xb = x + (size_t)b * Tn;
  float* gbase = GI + (size_t)b * NSn * G3n + j;

  int t = t0;
  for (; t + 2 <= t1; t += 2) {
    const float* xp0 = xb + t * 48;
    const float* xp1 = xp0 + 48;
    float a0 = bj, a1 = bj;
#pragma unroll
    for (int q = 0; q < 24; ++q) {
      f4 x0 = *(const f4*)&xp0[4 * q];           // uniform addr -> broadcast
      f4 x1 = *(const f4*)&xp1[4 * q];
      a0 = fmaf(x0[0], w[q][0], a0);
      a0 = fmaf(x0[1], w[q][1], a0);
      a0 = fmaf(x0[2], w[q][2], a0);
      a0 = fmaf(x0[3], w[q][3], a0);
      a1 = fmaf(x1[0], w[q][0], a1);
      a1 = fmaf(x1[1], w[q][1], a1);
      a1 = fmaf(x1[2], w[q][2], a1);
      a1 = fmaf(x1[3], w[q][3], a1);
    }
    gbase[(size_t)t * G3n]       = a0;           // 192 consecutive floats
    gbase[(size_t)(t + 1) * G3n] = a1;
  }
  for (; t < t1; ++t) {
    const float* xp = xb + t * 48;
    float a0 = bj;
#pragma unroll
    for (int q = 0; q < 24; ++q) {
      f4 xv = *(const f4*)&xp[4 * q];
      a0 = fmaf(xv[0], w[q][0], a0);
      a0 = fmaf(xv[1], w[q][1], a0);
      a0 = fmaf(xv[2], w[q][2], a0);
      a0 = fmaf(xv[3], w[q][3], a0);
    }
    gbase[(size_t)t * G3n] = a0;
  }
}

// ---------------------------------------------------------------------------
// GRU body (round-0 proven, 485us).
// ---------------------------------------------------------------------------
__device__ __forceinline__ float fsigmoid(float v) {
  return __fdividef(1.0f, 1.0f + __expf(-v));
}
__device__ __forceinline__ float ftanh_f(float v) {
  return 1.0f - __fdividef(2.0f, __expf(2.0f * v) + 1.0f);
}

__device__ __forceinline__ void gru_body(const float* __restrict__ GI,
                                         const float* __restrict__ W_hh,
                                         const float* __restrict__ b_hh,
                                         float* __restrict__ hs,
                                         float* hbuf, int b, int j) {
  f2 wr2[32], wz2[32], wn2[32];
  const f2* Wr = (const f2*)(W_hh + (size_t)j * 64);
  const f2* Wz = (const f2*)(W_hh + (size_t)(j + 64) * 64);
  const f2* Wn = (const f2*)(W_hh + (size_t)(j + 128) * 64);
#pragma unroll
  for (int q = 0; q < 32; ++q) { wr2[q] = Wr[q]; wz2[q] = Wz[q]; wn2[q] = Wn[q]; }
  // Opaque to the compiler => cannot re-load from memory inside the loop.
#pragma unroll
  for (int q = 0; q < 32; ++q) {
    asm volatile("" : "+v"(wr2[q]));
    asm volatile("" : "+v"(wz2[q]));
    asm volatile("" : "+v"(wn2[q]));
  }
  const float br = b_hh[j], bz = b_hh[j + 64], bn = b_hh[j + 128];

  hbuf[j] = 0.0f;
  float hj = 0.0f;
  __builtin_amdgcn_wave_barrier();

  const float* gp = GI + (size_t)b * NSn * G3n;
  float* hsp = hs + (size_t)b * NSn * GHn;

  // distance-2 prefetch ring
  float pr0, pr1, pr2, pz0, pz1, pz2, pn0, pn1, pn2;
  pr0 = gp[0 * G3n + j];       pz0 = gp[0 * G3n + 64 + j];  pn0 = gp[0 * G3n + 128 + j];
  pr1 = gp[1 * G3n + j];       pz1 = gp[1 * G3n + 64 + j];  pn1 = gp[1 * G3n + 128 + j];

  for (int t = 0; t < NSn; ++t) {
    const size_t off = (size_t)min(t + 2, NSn - 1) * G3n;
    pr2 = gp[off + j];
    pz2 = gp[off + 64 + j];
    pn2 = gp[off + 128 + j];

    const f2* h2 = (const f2*)hbuf;
    f2 ar0 = {0.f, 0.f}, ar1 = {0.f, 0.f}, ar2 = {0.f, 0.f}, ar3 = {0.f, 0.f};
    f2 az0 = {0.f, 0.f}, az1 = {0.f, 0.f}, az2 = {0.f, 0.f}, az3 = {0.f, 0.f};
    f2 an0 = {0.f, 0.f}, an1 = {0.f, 0.f}, an2 = {0.f, 0.f}, an3 = {0.f, 0.f};
#pragma unroll
    for (int q = 0; q < 8; ++q) {
      f2 h0 = h2[q * 4 + 0], h1 = h2[q * 4 + 1], h2v = h2[q * 4 + 2], h3 = h2[q * 4 + 3];
      ar0 += wr2[q * 4 + 0] * h0; ar1 += wr2[q * 4 + 1] * h1;
      ar2 += wr2[q * 4 + 2] * h2v; ar3 += wr2[q * 4 + 3] * h3;
      az0 += wz2[q * 4 + 0] * h0; az1 += wz2[q * 4 + 1] * h1;
      az2 += wz2[q * 4 + 2] * h2v; az3 += wz2[q * 4 + 3] * h3;
      an0 += wn2[q * 4 + 0] * h0; an1 += wn2[q * 4 + 1] * h1;
      an2 += wn2[q * 4 + 2] * h2v; an3 += wn2[q * 4 + 3] * h3;
    }
    f2 sr = (ar0 + ar1) + (ar2 + ar3);
    f2 sz = (az0 + az1) + (az2 + az3);
    f2 sn = (an0 + an1) + (an2 + an3);

    float r = fsigmoid(pr0 + br + sr.x + sr.y);
    float z = fsigmoid(pz0 + bz + sz.x + sz.y);
    float n = ftanh_f(fmaf(r, bn + sn.x + sn.y, pn0));
    float hn = fmaf(z, hj - n, n);          // (1-z)*n + z*h

    __builtin_amdgcn_wave_barrier();
    hbuf[j] = hn;
    __builtin_amdgcn_wave_barrier();
    hj = hn;
    hsp[(size_t)t * GHn + j] = hn;

    pr0 = pr1; pr1 = pr2;
    pz0 = pz1; pz1 = pz2;
    pn0 = pn1; pn1 = pn2;
  }
}

// Standalone gru (small-ws fallback path).
__global__ __attribute__((amdgpu_flat_work_group_size(64, 64),
                          amdgpu_waves_per_eu(1, 1),
                          amdgpu_num_vgpr(256)))
void gru_kernel(const float* __restrict__ GI,
                const float* __restrict__ W_hh,
                const float* __restrict__ b_hh,
                float* __restrict__ hs) {
  __shared__ __align__(16) float hbuf[64];
  gru_body(GI, W_hh, b_hh, hs, hbuf, blockIdx.x, threadIdx.x);
}

// ---------------------------------------------------------------------------
// FAT kernel (round-4 proven, 503us): blocks [0,128) gru; rest U filler.
// ---------------------------------------------------------------------------
constexpr int UCHUNK = 125;
constexpr int NCH    = 24;            // 24*125 = 3000 >= 2999

__global__ __attribute__((amdgpu_flat_work_group_size(64, 64),
                          amdgpu_waves_per_eu(1, 1),
                          amdgpu_num_vgpr(256)))
void fat_kernel(const float* __restrict__ GI,
                const float* __restrict__ W_hh,
                const float* __restrict__ b_hh,
                float* __restrict__ hs,
                const float* __restrict__ x,
                const float* __restrict__ W1,
                const float* __restrict__ b1,
                float* __restrict__ U) {
  __shared__ __align__(16) float hbuf[64];
  __shared__ __align__(16) float xs[UCHUNK * 16 + 16];   // 2016
  const int tid = threadIdx.x;

  if (blockIdx.x < Bn) {
    gru_body(GI, W_hh, b_hh, hs, hbuf, blockIdx.x, tid);
    return;
  }

  const int ub = blockIdx.x - Bn;
  const int b  = ub / NCH;
  const int ch = ub % NCH;
  const int fA = ch * UCHUNK;
  const int fE = min(fA + UCHUNK, NFn);
  const int o  = tid;

  const int nsamp = (fE - fA - 1) * 16 + 32;
  for (int i = tid; i < nsamp; i += 64)
    xs[i] = x[(size_t)b * Tn + fA * 16 + i];

  f4 w1f[8];
#pragma unroll
  for (int i = 0; i < 8; ++i)
    w1f[i] = *(const f4*)&W1[(size_t)o * 64 + 4 * i];
  const float bo = b1[o];
  __syncthreads();

  float* Up = U + ((size_t)b * NFn) * GHn + o;
  for (int f = fA; f < fE; ++f) {
    const f4* xq = (const f4*)&xs[(f - fA) * 16];
    float a0 = bo, a1 = 0.f, a2 = 0.f, a3 = 0.f;
#pragma unroll
    for (int i = 0; i < 8; ++i) {
      f4 xv = xq[i];
      a0 = fmaf(xv[0], w1f[i][0], a0);
      a1 = fmaf(xv[1], w1f[i][1], a1);
      a2 = fmaf(xv[2], w1f[i][2], a2);
      a3 = fmaf(xv[3], w1f[i][3], a3);
    }
    Up[(size_t)f * GHn] = (a0 + a1) + (a2 + a3);
  }
}

// ---------------------------------------------------------------------------
// d_kernel: d[b,ts,o] = (c_s @ W1_cond^T), c_s = hs @ W_cs^T + b_cs  (proven)
// ---------------------------------------------------------------------------
__global__ __launch_bounds__(256) void d_kernel(const float* __restrict__ hs,
                                                const float* __restrict__ W_cs,
                                                const float* __restrict__ b_cs,
                                                const float* __restrict__ W1,
                                                float* __restrict__ d) {
  __shared__ __align__(16) float WcT[64 * 36];   // [k][i] stride 36
  __shared__ __align__(16) float W1cT[32 * 68];  // [i][o] stride 68
  __shared__ __align__(16) float hsl[32 * 65];   // [t][k] stride 65
  __shared__ __align__(16) float cloc[32 * 36];  // [t][i] stride 36
  __shared__ __align__(16) float bcs[32];
  const int tile = blockIdx.x;   // 0..31
  const int b    = blockIdx.y;
  const int t0   = tile * 32;
  const int nt   = min(32, NSn - t0);
  const int tid  = threadIdx.x;

  for (int e = tid; e < 32 * 64; e += 256) {
    int i = e >> 6, k = e & 63;
    WcT[k * 36 + i] = W_cs[e];
  }
  for (int e = tid; e < 64 * 32; e += 256) {
    int o = e >> 5, i = e & 31;
    W1cT[i * 68 + o] = W1[(size_t)o * 64 + 32 + i];
  }
  for (int e = tid; e < nt * 64; e += 256) {
    int t = e >> 6, k = e & 63;
    hsl[t * 65 + k] = hs[((size_t)b * NSn + t0 + t) * GHn + k];
  }
  if (tid < 32) bcs[tid] = b_cs[tid];
  __syncthreads();

  {
    const int iq = tid & 7;
    const int t  = tid >> 3;
    if (t < nt) {
      float4 acc = *(const float4*)&bcs[iq * 4];
      const float* hr = &hsl[t * 65];
#pragma unroll 4
      for (int k = 0; k < 64; ++k) {
        float hv = hr[k];
        float4 w = *(const float4*)&WcT[k * 36 + iq * 4];
        acc.x = fmaf(w.x, hv, acc.x);
        acc.y = fmaf(w.y, hv, acc.y);
        acc.z = fmaf(w.z, hv, acc.z);
        acc.w = fmaf(w.w, hv, acc.w);
      }
      *(float4*)&cloc[t * 36 + iq * 4] = acc;
    }
  }
  __syncthreads();

  for (int it = tid; it < 32 * 16; it += 256) {
    const int oq = it & 15;
    const int t  = it >> 4;
    if (t < nt) {
      float a0 = 0.f, a1 = 0.f, a2 = 0.f, a3 = 0.f;
      const float* cr = &cloc[t * 36];
#pragma unroll 4
      for (int i = 0; i < 32; ++i) {
        float cv = cr[i];
        float4 w = *(const float4*)&W1cT[i * 68 + oq * 4];
        a0 = fmaf(w.x, cv, a0);
        a1 = fmaf(w.y, cv, a1);
        a2 = fmaf(w.z, cv, a2);
        a3 = fmaf(w.w, cv, a3);
      }
      float4 st = make_float4(a0, a1, a2, a3);
      *(float4*)&d[((size_t)b * NSn + t0 + t) * GHn + oq * 4] = st;
    }
  }
}

// ---------------------------------------------------------------------------
// cs_kernel (small-ws fallback only)
// ---------------------------------------------------------------------------
__global__ __launch_bounds__(256) void cs_kernel(const float* __restrict__ hs,
                                                 const float* __restrict__ W_cs,
                                                 const float* __restrict__ b_cs,
                                                 float* __restrict__ cs) {
  __shared__ __align__(16) float WcT[64 * 36];
  __shared__ __align__(16) float hsl[32 * 65];
  __shared__ __align__(16) float bcs[32];
  const int tile = blockIdx.x;
  const int b    = blockIdx.y;
  const int t0   = tile * 32;
  const int nt   = min(32, NSn - t0);
  const int tid  = threadIdx.x;

  for (int e = tid; e < 32 * 64; e += 256) {
    int i = e >> 6, k = e & 63;
    WcT[k * 36 + i] = W_cs[e];
  }
  for (int e = tid; e < nt * 64; e += 256) {
    int t = e >> 6, k = e & 63;
    hsl[t * 65 + k] = hs[((size_t)b * NSn + t0 + t) * GHn + k];
  }
  if (tid < 32) bcs[tid] = b_cs[tid];
  __syncthreads();

  const int oq = tid & 7;
  const int t  = tid >> 3;
  if (t < nt) {
    float4 acc = *(const float4*)&bcs[oq * 4];
    const float* hr = &hsl[t * 65];
#pragma unroll 4
    for (int k = 0; k < 64; ++k) {
      float hv = hr[k];
      float4 w = *(const float4*)&WcT[k * 36 + oq * 4];
      acc.x = fmaf(w.x, hv, acc.x);
      acc.y = fmaf(w.y, hv, acc.y);
      acc.z = fmaf(w.z, hv, acc.z);
      acc.w = fmaf(w.w, hv, acc.w);
    }
    *(float4*)&cs[((size_t)b * NSn + t0 + t) * 32 + oq * 4] = acc;
  }
}

// ---------------------------------------------------------------------------
// out2: h = relu(U + d[ts]), y = h@W2^T + b2, overlap-add  (proven)
// ---------------------------------------------------------------------------
__global__ __launch_bounds__(256) void out2_kernel(const float* __restrict__ U,
                                                   const float* __restrict__ d,
                                                   const float* __restrict__ W2,
                                                   const float* __restrict__ b2,
                                                   float* __restrict__ out) {
  __shared__ __align__(16) float h1loc[33 * 68];
  __shared__ __align__(16) float W2T[64 * 36];
  __shared__ __align__(16) float yloc[33 * 32];
  __shared__ __align__(16) float dloc[12][68];
  __shared__ __align__(16) float bb2[32];

  const int fb  = blockIdx.x;
  const int b   = blockIdx.y;
  const int f0  = fb * 32;
  const int nf  = min(33, NFn - f0);
  const int tid = threadIdx.x;
  const int ts0 = max(f0 / 3 - 1, 0);

  for (int e = tid; e < 32 * 64; e += 256) {
    int o = e >> 6, k = e & 63;
    W2T[k * 36 + o] = W2[e];
  }
  if (tid < 32) bb2[tid] = b2[tid];
  for (int e = tid; e < 12 * 64; e += 256) {
    int ti = e >> 6, o = e & 63;
    int ts = min(ts0 + ti, NSn - 1);
    dloc[ti][o] = d[((size_t)b * NSn + ts) * GHn + o];
  }
  __syncthreads();

  for (int it = tid; it < 33 * 16; it += 256) {
    const int lf = it >> 4, oq = it & 15;
    const int f  = f0 + lf;
    f4 s = {0.f, 0.f, 0.f, 0.f};
    if (f < NFn) {
      f4 u  = *(const f4*)&U[((size_t)b * NFn + f) * GHn + oq * 4];
      const int ti = max(f / 3 - 1, 0) - ts0;
      f4 dv = *(const f4*)&dloc[ti][oq * 4];
      s = u + dv;
#pragma unroll
      for (int c = 0; c < 4; ++c) s[c] = fmaxf(s[c], 0.f);
    }
    *(f4*)&h1loc[lf * 68 + oq * 4] = s;
  }
  __syncthreads();

  for (int it = tid; it < 33 * 8; it += 256) {
    const int lf = it >> 3, oq = it & 7;
    float4 acc = *(const float4*)&bb2[oq * 4];
    const float* hr = &h1loc[lf * 68];
#pragma unroll 4
    for (int k = 0; k < 64; ++k) {
      float hv = hr[k];
      float4 w = *(const float4*)&W2T[k * 36 + oq * 4];
      acc.x = fmaf(w.x, hv, acc.x);
      acc.y = fmaf(w.y, hv, acc.y);
      acc.z = fmaf(w.z, hv, acc.z);
      acc.w = fmaf(w.w, hv, acc.w);
    }
    *(float4*)&yloc[lf * 32 + oq * 4] = acc;
  }
  __syncthreads();

  const int s0 = f0 * 16 + 16;
  const int s1 = min(s0 + 512, Tn);
  for (int s = s0 + tid; s < s1; s += 256) {
    int f1  = s >> 4;
    int o1  = s & 15;
    int lf1 = f1 - f0;
    float v = yloc[(lf1 - 1) * 32 + o1 + 16];
    if (lf1 < nf) v += yloc[lf1 * 32 + o1];
    out[(size_t)b * Tn + s] = v;
  }
  if (fb == 0 && tid < 16) out[(size_t)b * Tn + tid] = yloc[tid];
}

// ---------------------------------------------------------------------------
// out_kernel (small-ws fallback only): round-0 fused MLP + OA
// ---------------------------------------------------------------------------
__global__ __launch_bounds__(256) void out_kernel(const float* __restrict__ x,
                                                  const float* __restrict__ cs,
                                                  const float* __restrict__ W1,
                                                  const float* __restrict__ b1,
                                                  const float* __restrict__ W2,
                                                  const float* __restrict__ b2,
                                                  float* __restrict__ out) {
  __shared__ __align__(16) float A[33 * 65];
  __shared__ __align__(16) float W1T[64 * 68];
  __shared__ __align__(16) float W2T[64 * 36];
  __shared__ __align__(16) float h1loc[33 * 65];
  __shared__ __align__(16) float yloc[33 * 32];
  __shared__ __align__(16) float bb1[64];
  __shared__ __align__(16) float bb2[32];

  const int fb  = blockIdx.x;
  const int b   = blockIdx.y;
  const int f0  = fb * 32;
  const int nf  = min(33, NFn - f0);
  const int tid = threadIdx.x;

  for (int e = tid; e < 64 * 64; e += 256) {
    int o = e >> 6, k = e & 63;
    W1T[k * 68 + o] = W1[e];
  }
  for (int e = tid; e < 32 * 64; e += 256) {
    int o = e >> 6, k = e & 63;
    W2T[k * 36 + o] = W2[e];
  }
  if (tid < 64) bb1[tid] = b1[tid];
  if (tid < 32) bb2[tid] = b2[tid];

  for (int e = tid; e < 33 * 32; e += 256) {
    int lf = e >> 5, k = e & 31;
    int g = (f0 + lf) * 16 + k;
    A[lf * 65 + k] = (lf < nf && g < Tn) ? x[(size_t)b * Tn + g] : 0.0f;
  }
  for (int e = tid; e < 33 * 32; e += 256) {
    int lf = e >> 5, k = e & 31;
    int ts = max((f0 + lf) / 3 - 1, 0);
    A[lf * 65 + 32 + k] = (lf < nf) ? cs[((size_t)b * NSn + ts) * 32 + k] : 0.0f;
  }
  __syncthreads();

  for (int it = tid; it < 33 * 16; it += 256) {
    int lf = it >> 4, oq = it & 15;
    float4 acc = *(const float4*)&bb1[oq * 4];
    const float* ar = &A[lf * 65];
#pragma unroll 4
    for (int k = 0; k < 64; ++k) {
      float av = ar[k];
      float4 w = *(const float4*)&W1T[k * 68 + oq * 4];
      acc.x = fmaf(w.x, av, acc.x);
      acc.y = fmaf(w.y, av, acc.y);
      acc.z = fmaf(w.z, av, acc.z);
      acc.w = fmaf(w.w, av, acc.w);
    }
    acc.x = fmaxf(acc.x, 0.0f); acc.y = fmaxf(acc.y, 0.0f);
    acc.z = fmaxf(acc.z, 0.0f); acc.w = fmaxf(acc.w, 0.0f);
    *(float4*)&h1loc[lf * 65 + oq * 4] = acc;
  }
  __syncthreads();

  for (int it = tid; it < 33 * 8; it += 256) {
    int lf = it >> 3, oq = it & 7;
    float4 acc = *(const float4*)&bb2[oq * 4];
    const float* hr = &h1loc[lf * 65];
#pragma unroll 4
    for (int k = 0; k < 64; ++k) {
      float hv = hr[k];
      float4 w = *(const float4*)&W2T[k * 36 + oq * 4];
      acc.x = fmaf(w.x, hv, acc.x);
      acc.y = fmaf(w.y, hv, acc.y);
      acc.z = fmaf(w.z, hv, acc.z);
      acc.w = fmaf(w.w, hv, acc.w);
    }
    *(float4*)&yloc[lf * 32 + oq * 4] = acc;
  }
  __syncthreads();

  const int s0 = f0 * 16 + 16;
  const int s1 = min(s0 + 512, Tn);
  for (int s = s0 + tid; s < s1; s += 256) {
    int f1  = s >> 4;
    int o1  = s & 15;
    int lf1 = f1 - f0;
    float v = yloc[(lf1 - 1) * 32 + o1 + 16];
    if (lf1 < nf) v += yloc[lf1 * 32 + o1];
    out[(size_t)b * Tn + s] = v;
  }
  if (fb == 0 && tid < 16) out[(size_t)b * Tn + tid] = yloc[tid];
}

// ---------------------------------------------------------------------------
extern "C" void kernel_launch(void* const* d_in, const int* in_sizes, int n_in,
                              void* d_out, int out_size, void* d_ws, size_t ws_size,
                              hipStream_t stream) {
  const float* x    = (const float*)d_in[0];
  const float* W_ih = (const float*)d_in[1];
  const float* W_hh = (const float*)d_in[2];
  const float* b_ih = (const float*)d_in[3];
  const float* b_hh = (const float*)d_in[4];
  const float* W_cs = (const float*)d_in[5];
  const float* b_cs = (const float*)d_in[6];
  const float* W1   = (const float*)d_in[7];
  const float* b1   = (const float*)d_in[8];
  const float* W2   = (const float*)d_in[9];
  const float* b2   = (const float*)d_in[10];
  float* out = (float*)d_out;

  const size_t giN = (size_t)Bn * NSn * G3n;   // 98.2 MB
  const size_t hsN = (size_t)Bn * NSn * GHn;   // 32.7 MB
  const size_t uN  = (size_t)Bn * NFn * GHn;   // 98.3 MB

  float* GI = (float*)d_ws;
  float* hs = GI + giN;

  gi2_kernel<<<dim3(GI_NC, Bn), 192, 0, stream>>>(x, W_ih, b_ih, GI);

  if (ws_size >= (giN + hsN + uN) * sizeof(float)) {
    // Round-4 proven fast path: gru overlapped with U precompute.
    float* U = hs + hsN;
    float* d = GI;                             // GI dead after fat
    fat_kernel<<<Bn + Bn * NCH, 64, 0, stream>>>(GI, W_hh, b_hh, hs,
                                                 x, W1, b1, U);
    d_kernel<<<dim3(32, Bn), 256, 0, stream>>>(hs, W_cs, b_cs, W1, d);
    out2_kernel<<<dim3(94, Bn), 256, 0, stream>>>(U, d, W2, b2, out);
  } else {
    // Small-ws fallback: round-0 pipeline.
    float* cs = GI;
    gru_kernel<<<Bn, 64, 0, stream>>>(GI, W_hh, b_hh, hs);
    cs_kernel<<<dim3(32, Bn), 256, 0, stream>>>(hs, W_cs, b_cs, cs);
    out_kernel<<<dim3(94, Bn), 256, 0, stream>>>(x, cs, W1, b1, W2, b2, out);
  }
}

// Round 8
// 767.951 us; speedup vs baseline: 1.7498x; 1.1330x over previous
//
#include <hip/hip_runtime.h>

// Problem constants
constexpr int Bn  = 128;
constexpr int Tn  = 48000;
constexpr int NFn = 2999;   // fast frames
constexpr int NSn = 999;    // slow frames
constexpr int G3n = 192;    // 3*GH
constexpr int GHn = 64;

typedef float f2 __attribute__((ext_vector_type(2)));
typedef float f4 __attribute__((ext_vector_type(4)));

// ---------------------------------------------------------------------------
// Kernel 1: GI[b,t,j] = b_ih[j] + sum_{k<96} x[b,t*48+k] * W_ih[j,k]
// Round-0 structure (proven correct) with the DS-issue fix: k chunked by 4
// so xs is read as b128 quads instead of 8 scalar b32 per k. DS-instr per
// 128 FMAs drops 36 -> 12 (same bytes; xs quads are wave-uniform per (tg,u)
// -> LDS broadcast). Per-accumulator FMA order remains exactly k-ascending
// => bitwise-identical GI. (gi2 W-stationary variant REFUTED in r7: 244us —
// 2-deep FMA chains + dependent VMEM loads; this targets ~90us from 145.)
// ---------------------------------------------------------------------------
__global__ __launch_bounds__(192) void gi_kernel(const float* __restrict__ x,
                                                 const float* __restrict__ W_ih,
                                                 const float* __restrict__ b_ih,
                                                 float* __restrict__ GI) {
  __shared__ __align__(16) float WT[48 * 196];   // [k][j] padded stride 196
  __shared__ __align__(16) float xs[1584];       // 31*48+96 samples
  const int tile = blockIdx.x;        // 0..31
  const int b    = blockIdx.y;        // 0..127
  const int t0   = tile * 32;
  const int nt   = min(32, NSn - t0); // 32 or 7 (last tile)
  const int tid  = threadIdx.x;

  const int span = (nt - 1) * 48 + 96;
  for (int i = tid; i < 1584; i += 192)
    xs[i] = (i < span) ? x[(size_t)b * Tn + t0 * 48 + i] : 0.0f;

  const int jq = tid % 48;   // j-quad index
  const int tg = tid / 48;   // t-group (0..3)
  const int j0 = jq * 4;

  float acc[8][4];
#pragma unroll
  for (int u = 0; u < 8; ++u)
#pragma unroll
    for (int jj = 0; jj < 4; ++jj) acc[u][jj] = b_ih[j0 + jj];

  for (int half = 0; half < 2; ++half) {
    __syncthreads();
    for (int e = tid; e < 192 * 48; e += 192) {
      int j = e / 48, k = e % 48;
      WT[k * 196 + j] = W_ih[j * 96 + half * 48 + k];
    }
    __syncthreads();
    for (int kc = 0; kc < 48; kc += 4) {
      // 4 W quads (b128 each; 196%4==0, j0%4==0 -> 16B aligned)
      f4 wq[4];
#pragma unroll
      for (int kk = 0; kk < 4; ++kk)
        wq[kk] = *(const f4*)&WT[(kc + kk) * 196 + j0];
      // 8 xs quads (b128; addr uniform over jq -> LDS broadcast)
      f4 xq[8];
#pragma unroll
      for (int u = 0; u < 8; ++u)
        xq[u] = *(const f4*)&xs[(tg * 8 + u) * 48 + half * 48 + kc];
      // FMAs: per acc[u][jj] the k order is kc+0,1,2,3 ascending — identical
      // to the original per-k loop => bitwise-identical accumulation.
#pragma unroll
      for (int u = 0; u < 8; ++u) {
#pragma unroll
        for (int kk = 0; kk < 4; ++kk) {
          const float xv = xq[u][kk];
          acc[u][0] = fmaf(xv, wq[kk][0], acc[u][0]);
          acc[u][1] = fmaf(xv, wq[kk][1], acc[u][1]);
          acc[u][2] = fmaf(xv, wq[kk][2], acc[u][2]);
          acc[u][3] = fmaf(xv, wq[kk][3], acc[u][3]);
        }
      }
    }
  }

#pragma unroll
  for (int u = 0; u < 8; ++u) {
    int tl = tg * 8 + u;
    if (tl < nt) {
      float4 st = make_float4(acc[u][0], acc[u][1], acc[u][2], acc[u][3]);
      *(float4*)&GI[(size_t)(b * NSn + t0 + tl) * G3n + j0] = st;
    }
  }
}

// ---------------------------------------------------------------------------
// GRU body (round-0 proven, 485us).
// ---------------------------------------------------------------------------
__device__ __forceinline__ float fsigmoid(float v) {
  return __fdividef(1.0f, 1.0f + __expf(-v));
}
__device__ __forceinline__ float ftanh_f(float v) {
  return 1.0f - __fdividef(2.0f, __expf(2.0f * v) + 1.0f);
}

__device__ __forceinline__ void gru_body(const float* __restrict__ GI,
                                         const float* __restrict__ W_hh,
                                         const float* __restrict__ b_hh,
                                         float* __restrict__ hs,
                                         float* hbuf, int b, int j) {
  f2 wr2[32], wz2[32], wn2[32];
  const f2* Wr = (const f2*)(W_hh + (size_t)j * 64);
  const f2* Wz = (const f2*)(W_hh + (size_t)(j + 64) * 64);
  const f2* Wn = (const f2*)(W_hh + (size_t)(j + 128) * 64);
#pragma unroll
  for (int q = 0; q < 32; ++q) { wr2[q] = Wr[q]; wz2[q] = Wz[q]; wn2[q] = Wn[q]; }
  // Opaque to the compiler => cannot re-load from memory inside the loop.
#pragma unroll
  for (int q = 0; q < 32; ++q) {
    asm volatile("" : "+v"(wr2[q]));
    asm volatile("" : "+v"(wz2[q]));
    asm volatile("" : "+v"(wn2[q]));
  }
  const float br = b_hh[j], bz = b_hh[j + 64], bn = b_hh[j + 128];

  hbuf[j] = 0.0f;
  float hj = 0.0f;
  __builtin_amdgcn_wave_barrier();

  const float* gp = GI + (size_t)b * NSn * G3n;
  float* hsp = hs + (size_t)b * NSn * GHn;

  // distance-2 prefetch ring
  float pr0, pr1, pr2, pz0, pz1, pz2, pn0, pn1, pn2;
  pr0 = gp[0 * G3n + j];       pz0 = gp[0 * G3n + 64 + j];  pn0 = gp[0 * G3n + 128 + j];
  pr1 = gp[1 * G3n + j];       pz1 = gp[1 * G3n + 64 + j];  pn1 = gp[1 * G3n + 128 + j];

  for (int t = 0; t < NSn; ++t) {
    const size_t off = (size_t)min(t + 2, NSn - 1) * G3n;
    pr2 = gp[off + j];
    pz2 = gp[off + 64 + j];
    pn2 = gp[off + 128 + j];

    const f2* h2 = (const f2*)hbuf;
    f2 ar0 = {0.f, 0.f}, ar1 = {0.f, 0.f}, ar2 = {0.f, 0.f}, ar3 = {0.f, 0.f};
    f2 az0 = {0.f, 0.f}, az1 = {0.f, 0.f}, az2 = {0.f, 0.f}, az3 = {0.f, 0.f};
    f2 an0 = {0.f, 0.f}, an1 = {0.f, 0.f}, an2 = {0.f, 0.f}, an3 = {0.f, 0.f};
#pragma unroll
    for (int q = 0; q < 8; ++q) {
      f2 h0 = h2[q * 4 + 0], h1 = h2[q * 4 + 1], h2v = h2[q * 4 + 2], h3 = h2[q * 4 + 3];
      ar0 += wr2[q * 4 + 0] * h0; ar1 += wr2[q * 4 + 1] * h1;
      ar2 += wr2[q * 4 + 2] * h2v; ar3 += wr2[q * 4 + 3] * h3;
      az0 += wz2[q * 4 + 0] * h0; az1 += wz2[q * 4 + 1] * h1;
      az2 += wz2[q * 4 + 2] * h2v; az3 += wz2[q * 4 + 3] * h3;
      an0 += wn2[q * 4 + 0] * h0; an1 += wn2[q * 4 + 1] * h1;
      an2 += wn2[q * 4 + 2] * h2v; an3 += wn2[q * 4 + 3] * h3;
    }
    f2 sr = (ar0 + ar1) + (ar2 + ar3);
    f2 sz = (az0 + az1) + (az2 + az3);
    f2 sn = (an0 + an1) + (an2 + an3);

    float r = fsigmoid(pr0 + br + sr.x + sr.y);
    float z = fsigmoid(pz0 + bz + sz.x + sz.y);
    float n = ftanh_f(fmaf(r, bn + sn.x + sn.y, pn0));
    float hn = fmaf(z, hj - n, n);          // (1-z)*n + z*h

    __builtin_amdgcn_wave_barrier();
    hbuf[j] = hn;
    __builtin_amdgcn_wave_barrier();
    hj = hn;
    hsp[(size_t)t * GHn + j] = hn;

    pr0 = pr1; pr1 = pr2;
    pz0 = pz1; pz1 = pz2;
    pn0 = pn1; pn1 = pn2;
  }
}

// Standalone gru (small-ws fallback path).
__global__ __attribute__((amdgpu_flat_work_group_size(64, 64),
                          amdgpu_waves_per_eu(1, 1),
                          amdgpu_num_vgpr(256)))
void gru_kernel(const float* __restrict__ GI,
                const float* __restrict__ W_hh,
                const float* __restrict__ b_hh,
                float* __restrict__ hs) {
  __shared__ __align__(16) float hbuf[64];
  gru_body(GI, W_hh, b_hh, hs, hbuf, blockIdx.x, threadIdx.x);
}

// ---------------------------------------------------------------------------
// FAT kernel (round-4 proven, 503us): blocks [0,128) gru; rest U filler.
// NEW: gru waves run at s_setprio(1) so the SIMD arbiter favors the serial
// pole over co-resident U-filler waves (the measured +18us r0->r4
// interference window). U waves stay at default prio 0.
// ---------------------------------------------------------------------------
constexpr int UCHUNK = 125;
constexpr int NCH    = 24;            // 24*125 = 3000 >= 2999

__global__ __attribute__((amdgpu_flat_work_group_size(64, 64),
                          amdgpu_waves_per_eu(1, 1),
                          amdgpu_num_vgpr(256)))
void fat_kernel(const float* __restrict__ GI,
                const float* __restrict__ W_hh,
                const float* __restrict__ b_hh,
                float* __restrict__ hs,
                const float* __restrict__ x,
                const float* __restrict__ W1,
                const float* __restrict__ b1,
                float* __restrict__ U) {
  __shared__ __align__(16) float hbuf[64];
  __shared__ __align__(16) float xs[UCHUNK * 16 + 16];   // 2016
  const int tid = threadIdx.x;

  if (blockIdx.x < Bn) {
    __builtin_amdgcn_s_setprio(1);     // favor the serial GRU pole
    gru_body(GI, W_hh, b_hh, hs, hbuf, blockIdx.x, tid);
    __builtin_amdgcn_s_setprio(0);
    return;
  }

  const int ub = blockIdx.x - Bn;
  const int b  = ub / NCH;
  const int ch = ub % NCH;
  const int fA = ch * UCHUNK;
  const int fE = min(fA + UCHUNK, NFn);
  const int o  = tid;

  const int nsamp = (fE - fA - 1) * 16 + 32;
  for (int i = tid; i < nsamp; i += 64)
    xs[i] = x[(size_t)b * Tn + fA * 16 + i];

  f4 w1f[8];
#pragma unroll
  for (int i = 0; i < 8; ++i)
    w1f[i] = *(const f4*)&W1[(size_t)o * 64 + 4 * i];
  const float bo = b1[o];
  __syncthreads();

  float* Up = U + ((size_t)b * NFn) * GHn + o;
  for (int f = fA; f < fE; ++f) {
    const f4* xq = (const f4*)&xs[(f - fA) * 16];
    float a0 = bo, a1 = 0.f, a2 = 0.f, a3 = 0.f;
#pragma unroll
    for (int i = 0; i < 8; ++i) {
      f4 xv = xq[i];
      a0 = fmaf(xv[0], w1f[i][0], a0);
      a1 = fmaf(xv[1], w1f[i][1], a1);
      a2 = fmaf(xv[2], w1f[i][2], a2);
      a3 = fmaf(xv[3], w1f[i][3], a3);
    }
    Up[(size_t)f * GHn] = (a0 + a1) + (a2 + a3);
  }
}

// ---------------------------------------------------------------------------
// d_kernel: d[b,ts,o] = (c_s @ W1_cond^T), c_s = hs @ W_cs^T + b_cs  (proven)
// ---------------------------------------------------------------------------
__global__ __launch_bounds__(256) void d_kernel(const float* __restrict__ hs,
                                                const float* __restrict__ W_cs,
                                                const float* __restrict__ b_cs,
                                                const float* __restrict__ W1,
                                                float* __restrict__ d) {
  __shared__ __align__(16) float WcT[64 * 36];   // [k][i] stride 36
  __shared__ __align__(16) float W1cT[32 * 68];  // [i][o] stride 68
  __shared__ __align__(16) float hsl[32 * 65];   // [t][k] stride 65
  __shared__ __align__(16) float cloc[32 * 36];  // [t][i] stride 36
  __shared__ __align__(16) float bcs[32];
  const int tile = blockIdx.x;   // 0..31
  const int b    = blockIdx.y;
  const int t0   = tile * 32;
  const int nt   = min(32, NSn - t0);
  const int tid  = threadIdx.x;

  for (int e = tid; e < 32 * 64; e += 256) {
    int i = e >> 6, k = e & 63;
    WcT[k * 36 + i] = W_cs[e];
  }
  for (int e = tid; e < 64 * 32; e += 256) {
    int o = e >> 5, i = e & 31;
    W1cT[i * 68 + o] = W1[(size_t)o * 64 + 32 + i];
  }
  for (int e = tid; e < nt * 64; e += 256) {
    int t = e >> 6, k = e & 63;
    hsl[t * 65 + k] = hs[((size_t)b * NSn + t0 + t) * GHn + k];
  }
  if (tid < 32) bcs[tid] = b_cs[tid];
  __syncthreads();

  {
    const int iq = tid & 7;
    const int t  = tid >> 3;
    if (t < nt) {
      float4 acc = *(const float4*)&bcs[iq * 4];
      const float* hr = &hsl[t * 65];
#pragma unroll 4
      for (int k = 0; k < 64; ++k) {
        float hv = hr[k];
        float4 w = *(const float4*)&WcT[k * 36 + iq * 4];
        acc.x = fmaf(w.x, hv, acc.x);
        acc.y = fmaf(w.y, hv, acc.y);
        acc.z = fmaf(w.z, hv, acc.z);
        acc.w = fmaf(w.w, hv, acc.w);
      }
      *(float4*)&cloc[t * 36 + iq * 4] = acc;
    }
  }
  __syncthreads();

  for (int it = tid; it < 32 * 16; it += 256) {
    const int oq = it & 15;
    const int t  = it >> 4;
    if (t < nt) {
      float a0 = 0.f, a1 = 0.f, a2 = 0.f, a3 = 0.f;
      const float* cr = &cloc[t * 36];
#pragma unroll 4
      for (int i = 0; i < 32; ++i) {
        float cv = cr[i];
        float4 w = *(const float4*)&W1cT[i * 68 + oq * 4];
        a0 = fmaf(w.x, cv, a0);
        a1 = fmaf(w.y, cv, a1);
        a2 = fmaf(w.z, cv, a2);
        a3 = fmaf(w.w, cv, a3);
      }
      float4 st = make_float4(a0, a1, a2, a3);
      *(float4*)&d[((size_t)b * NSn + t0 + t) * GHn + oq * 4] = st;
    }
  }
}

// ---------------------------------------------------------------------------
// cs_kernel (small-ws fallback only)
// ---------------------------------------------------------------------------
__global__ __launch_bounds__(256) void cs_kernel(const float* __restrict__ hs,
                                                 const float* __restrict__ W_cs,
                                                 const float* __restrict__ b_cs,
                                                 float* __restrict__ cs) {
  __shared__ __align__(16) float WcT[64 * 36];
  __shared__ __align__(16) float hsl[32 * 65];
  __shared__ __align__(16) float bcs[32];
  const int tile = blockIdx.x;
  const int b    = blockIdx.y;
  const int t0   = tile * 32;
  const int nt   = min(32, NSn - t0);
  const int tid  = threadIdx.x;

  for (int e = tid; e < 32 * 64; e += 256) {
    int i = e >> 6, k = e & 63;
    WcT[k * 36 + i] = W_cs[e];
  }
  for (int e = tid; e < nt * 64; e += 256) {
    int t = e >> 6, k = e & 63;
    hsl[t * 65 + k] = hs[((size_t)b * NSn + t0 + t) * GHn + k];
  }
  if (tid < 32) bcs[tid] = b_cs[tid];
  __syncthreads();

  const int oq = tid & 7;
  const int t  = tid >> 3;
  if (t < nt) {
    float4 acc = *(const float4*)&bcs[oq * 4];
    const float* hr = &hsl[t * 65];
#pragma unroll 4
    for (int k = 0; k < 64; ++k) {
      float hv = hr[k];
      float4 w = *(const float4*)&WcT[k * 36 + oq * 4];
      acc.x = fmaf(w.x, hv, acc.x);
      acc.y = fmaf(w.y, hv, acc.y);
      acc.z = fmaf(w.z, hv, acc.z);
      acc.w = fmaf(w.w, hv, acc.w);
    }
    *(float4*)&cs[((size_t)b * NSn + t0 + t) * 32 + oq * 4] = acc;
  }
}

// ---------------------------------------------------------------------------
// out2: h = relu(U + d[ts]), y = h@W2^T + b2, overlap-add  (proven)
// ---------------------------------------------------------------------------
__global__ __launch_bounds__(256) void out2_kernel(const float* __restrict__ U,
                                                   const float* __restrict__ d,
                                                   const float* __restrict__ W2,
                                                   const float* __restrict__ b2,
                                                   float* __restrict__ out) {
  __shared__ __align__(16) float h1loc[33 * 68];
  __shared__ __align__(16) float W2T[64 * 36];
  __shared__ __align__(16) float yloc[33 * 32];
  __shared__ __align__(16) float dloc[12][68];
  __shared__ __align__(16) float bb2[32];

  const int fb  = blockIdx.x;
  const int b   = blockIdx.y;
  const int f0  = fb * 32;
  const int nf  = min(33, NFn - f0);
  const int tid = threadIdx.x;
  const int ts0 = max(f0 / 3 - 1, 0);

  for (int e = tid; e < 32 * 64; e += 256) {
    int o = e >> 6, k = e & 63;
    W2T[k * 36 + o] = W2[e];
  }
  if (tid < 32) bb2[tid] = b2[tid];
  for (int e = tid; e < 12 * 64; e += 256) {
    int ti = e >> 6, o = e & 63;
    int ts = min(ts0 + ti, NSn - 1);
    dloc[ti][o] = d[((size_t)b * NSn + ts) * GHn + o];
  }
  __syncthreads();

  for (int it = tid; it < 33 * 16; it += 256) {
    const int lf = it >> 4, oq = it & 15;
    const int f  = f0 + lf;
    f4 s = {0.f, 0.f, 0.f, 0.f};
    if (f < NFn) {
      f4 u  = *(const f4*)&U[((size_t)b * NFn + f) * GHn + oq * 4];
      const int ti = max(f / 3 - 1, 0) - ts0;
      f4 dv = *(const f4*)&dloc[ti][oq * 4];
      s = u + dv;
#pragma unroll
      for (int c = 0; c < 4; ++c) s[c] = fmaxf(s[c], 0.f);
    }
    *(f4*)&h1loc[lf * 68 + oq * 4] = s;
  }
  __syncthreads();

  for (int it = tid; it < 33 * 8; it += 256) {
    const int lf = it >> 3, oq = it & 7;
    float4 acc = *(const float4*)&bb2[oq * 4];
    const float* hr = &h1loc[lf * 68];
#pragma unroll 4
    for (int k = 0; k < 64; ++k) {
      float hv = hr[k];
      float4 w = *(const float4*)&W2T[k * 36 + oq * 4];
      acc.x = fmaf(w.x, hv, acc.x);
      acc.y = fmaf(w.y, hv, acc.y);
      acc.z = fmaf(w.z, hv, acc.z);
      acc.w = fmaf(w.w, hv, acc.w);
    }
    *(float4*)&yloc[lf * 32 + oq * 4] = acc;
  }
  __syncthreads();

  const int s0 = f0 * 16 + 16;
  const int s1 = min(s0 + 512, Tn);
  for (int s = s0 + tid; s < s1; s += 256) {
    int f1  = s >> 4;
    int o1  = s & 15;
    int lf1 = f1 - f0;
    float v = yloc[(lf1 - 1) * 32 + o1 + 16];
    if (lf1 < nf) v += yloc[lf1 * 32 + o1];
    out[(size_t)b * Tn + s] = v;
  }
  if (fb == 0 && tid < 16) out[(size_t)b * Tn + tid] = yloc[tid];
}

// ---------------------------------------------------------------------------
// out_kernel (small-ws fallback only): round-0 fused MLP + OA
// ---------------------------------------------------------------------------
__global__ __launch_bounds__(256) void out_kernel(const float* __restrict__ x,
                                                  const float* __restrict__ cs,
                                                  const float* __restrict__ W1,
                                                  const float* __restrict__ b1,
                                                  const float* __restrict__ W2,
                                                  const float* __restrict__ b2,
                                                  float* __restrict__ out) {
  __shared__ __align__(16) float A[33 * 65];
  __shared__ __align__(16) float W1T[64 * 68];
  __shared__ __align__(16) float W2T[64 * 36];
  __shared__ __align__(16) float h1loc[33 * 65];
  __shared__ __align__(16) float yloc[33 * 32];
  __shared__ __align__(16) float bb1[64];
  __shared__ __align__(16) float bb2[32];

  const int fb  = blockIdx.x;
  const int b   = blockIdx.y;
  const int f0  = fb * 32;
  const int nf  = min(33, NFn - f0);
  const int tid = threadIdx.x;

  for (int e = tid; e < 64 * 64; e += 256) {
    int o = e >> 6, k = e & 63;
    W1T[k * 68 + o] = W1[e];
  }
  for (int e = tid; e < 32 * 64; e += 256) {
    int o = e >> 6, k = e & 63;
    W2T[k * 36 + o] = W2[e];
  }
  if (tid < 64) bb1[tid] = b1[tid];
  if (tid < 32) bb2[tid] = b2[tid];

  for (int e = tid; e < 33 * 32; e += 256) {
    int lf = e >> 5, k = e & 31;
    int g = (f0 + lf) * 16 + k;
    A[lf * 65 + k] = (lf < nf && g < Tn) ? x[(size_t)b * Tn + g] : 0.0f;
  }
  for (int e = tid; e < 33 * 32; e += 256) {
    int lf = e >> 5, k = e & 31;
    int ts = max((f0 + lf) / 3 - 1, 0);
    A[lf * 65 + 32 + k] = (lf < nf) ? cs[((size_t)b * NSn + ts) * 32 + k] : 0.0f;
  }
  __syncthreads();

  for (int it = tid; it < 33 * 16; it += 256) {
    int lf = it >> 4, oq = it & 15;
    float4 acc = *(const float4*)&bb1[oq * 4];
    const float* ar = &A[lf * 65];
#pragma unroll 4
    for (int k = 0; k < 64; ++k) {
      float av = ar[k];
      float4 w = *(const float4*)&W1T[k * 68 + oq * 4];
      acc.x = fmaf(w.x, av, acc.x);
      acc.y = fmaf(w.y, av, acc.y);
      acc.z = fmaf(w.z, av, acc.z);
      acc.w = fmaf(w.w, av, acc.w);
    }
    acc.x = fmaxf(acc.x, 0.0f); acc.y = fmaxf(acc.y, 0.0f);
    acc.z = fmaxf(acc.z, 0.0f); acc.w = fmaxf(acc.w, 0.0f);
    *(float4*)&h1loc[lf * 65 + oq * 4] = acc;
  }
  __syncthreads();

  for (int it = tid; it < 33 * 8; it += 256) {
    int lf = it >> 3, oq = it & 7;
    float4 acc = *(const float4*)&bb2[oq * 4];
    const float* hr = &h1loc[lf * 65];
#pragma unroll 4
    for (int k = 0; k < 64; ++k) {
      float hv = hr[k];
      float4 w = *(const float4*)&W2T[k * 36 + oq * 4];
      acc.x = fmaf(w.x, hv, acc.x);
      acc.y = fmaf(w.y, hv, acc.y);
      acc.z = fmaf(w.z, hv, acc.z);
      acc.w = fmaf(w.w, hv, acc.w);
    }
    *(float4*)&yloc[lf * 32 + oq * 4] = acc;
  }
  __syncthreads();

  const int s0 = f0 * 16 + 16;
  const int s1 = min(s0 + 512, Tn);
  for (int s = s0 + tid; s < s1; s += 256) {
    int f1  = s >> 4;
    int o1  = s & 15;
    int lf1 = f1 - f0;
    float v = yloc[(lf1 - 1) * 32 + o1 + 16];
    if (lf1 < nf) v += yloc[lf1 * 32 + o1];
    out[(size_t)b * Tn + s] = v;
  }
  if (fb == 0 && tid < 16) out[(size_t)b * Tn + tid] = yloc[tid];
}

// ---------------------------------------------------------------------------
extern "C" void kernel_launch(void* const* d_in, const int* in_sizes, int n_in,
                              void* d_out, int out_size, void* d_ws, size_t ws_size,
                              hipStream_t stream) {
  const float* x    = (const float*)d_in[0];
  const float* W_ih = (const float*)d_in[1];
  const float* W_hh = (const float*)d_in[2];
  const float* b_ih = (const float*)d_in[3];
  const float* b_hh = (const float*)d_in[4];
  const float* W_cs = (const float*)d_in[5];
  const float* b_cs = (const float*)d_in[6];
  const float* W1   = (const float*)d_in[7];
  const float* b1   = (const float*)d_in[8];
  const float* W2   = (const float*)d_in[9];
  const float* b2   = (const float*)d_in[10];
  float* out = (float*)d_out;

  const size_t giN = (size_t)Bn * NSn * G3n;   // 98.2 MB
  const size_t hsN = (size_t)Bn * NSn * GHn;   // 32.7 MB
  const size_t uN  = (size_t)Bn * NFn * GHn;   // 98.3 MB

  float* GI = (float*)d_ws;
  float* hs = GI + giN;

  gi_kernel<<<dim3(32, Bn), 192, 0, stream>>>(x, W_ih, b_ih, GI);

  if (ws_size >= (giN + hsN + uN) * sizeof(float)) {
    // Round-4 proven fast path: gru overlapped with U precompute.
    float* U = hs + hsN;
    float* d = GI;                             // GI dead after fat
    fat_kernel<<<Bn + Bn * NCH, 64, 0, stream>>>(GI, W_hh, b_hh, hs,
                                                 x, W1, b1, U);
    d_kernel<<<dim3(32, Bn), 256, 0, stream>>>(hs, W_cs, b_cs, W1, d);
    out2_kernel<<<dim3(94, Bn), 256, 0, stream>>>(U, d, W2, b2, out);
  } else {
    // Small-ws fallback: round-0 pipeline.
    float* cs = GI;
    gru_kernel<<<Bn, 64, 0, stream>>>(GI, W_hh, b_hh, hs);
    cs_kernel<<<dim3(32, Bn), 256, 0, stream>>>(hs, W_cs, b_cs, cs);
    out_kernel<<<dim3(94, Bn), 256, 0, stream>>>(x, cs, W1, b1, W2, b2, out);
  }
}